// Round 4
// baseline (37.802 us; speedup 1.0000x reference)
//
#include <hip/hip_runtime.h>

#define NPART   8192
#define NSPLITJ 32                  // j-splits
#define JCHUNK  (NPART / NSPLITJ)   // 256 j's per block (4 per lane)
#define ITILES  (NPART / 256)       // 32 i-tiles

// Broadcast lane k's value to all lanes (k wave-uniform) -> v_readlane, no memory.
__device__ __forceinline__ float bcast_lane(float v, int k) {
    return __uint_as_float(__builtin_amdgcn_readlane(__float_as_uint(v), k));
}

// All-pairs kernel, register-resident (no LDS in the inner loop).
// Each lane holds 4 j-positions in VGPRs; each wave handles 64 i's, one per
// iteration, broadcasting lane k's i-position via v_readlane. Per iteration a
// wave covers 256 pairs for one i; whole-wave early exit skips sqrt+poly when
// no pair is inside the cutoff (w == 0 exactly for r^2 > 0.01).
// Cubic spline identity: w(q) = 2*max(1-q,0)^3 - max(1-2q,0)^3, q = 10 r.
__global__ __launch_bounds__(256) void sph_pairs(const float* __restrict__ pos,
                                                 float* __restrict__ ws) {
    const int tid  = threadIdx.x;
    const int lane = tid & 63;
    const int wv   = tid >> 6;           // wave id in block, 0..3
    const int bi   = blockIdx.x;         // i-tile  [0,32)
    const int bj   = blockIdx.y;         // j-chunk [0,32)

    // Lane-private j-positions: j = bj*256 + 4*lane .. +3  (12 floats = 3 float4,
    // byte offset 12*(256*bj + 4*lane) = 3072*bj + 48*lane, 16B-aligned).
    const float4* jp = (const float4*)(pos + (size_t)(bj * JCHUNK + 4 * lane) * 3);
    const float4 t0 = jp[0], t1 = jp[1], t2 = jp[2];
    const float jx0 = t0.x, jy0 = t0.y, jz0 = t0.z;
    const float jx1 = t0.w, jy1 = t1.x, jz1 = t1.y;
    const float jx2 = t1.z, jy2 = t1.w, jz2 = t2.x;
    const float jx3 = t2.y, jy3 = t2.z, jz3 = t2.w;

    // Lane-held i-position for i = ibase + lane (broadcast source).
    const int ibase = bi * 256 + wv * 64;
    const float ipx = pos[3 * (ibase + lane) + 0];
    const float ipy = pos[3 * (ibase + lane) + 1];
    const float ipz = pos[3 * (ibase + lane) + 2];

    const float RCUT2 = 0.0100001f;      // (h=0.1)^2 + margin; w==0 beyond
    float accown = 0.0f;                 // density partial for i = ibase + lane

    for (int k = 0; k < 64; ++k) {
        const float sx = bcast_lane(ipx, k);
        const float sy = bcast_lane(ipy, k);
        const float sz = bcast_lane(ipz, k);

        const float dx0 = sx - jx0, dy0 = sy - jy0, dz0 = sz - jz0;
        const float dx1 = sx - jx1, dy1 = sy - jy1, dz1 = sz - jz1;
        const float dx2 = sx - jx2, dy2 = sy - jy2, dz2 = sz - jz2;
        const float dx3 = sx - jx3, dy3 = sy - jy3, dz3 = sz - jz3;

        const float d20 = fmaf(dx0, dx0, fmaf(dy0, dy0, fmaf(dz0, dz0, 1e-10f)));
        const float d21 = fmaf(dx1, dx1, fmaf(dy1, dy1, fmaf(dz1, dz1, 1e-10f)));
        const float d22 = fmaf(dx2, dx2, fmaf(dy2, dy2, fmaf(dz2, dz2, 1e-10f)));
        const float d23 = fmaf(dx3, dx3, fmaf(dy3, dy3, fmaf(dz3, dz3, 1e-10f)));

        const float m = fminf(fminf(d20, d21), fminf(d22, d23));
        if (__any(m <= RCUT2)) {
            // Rare path: clamped cubics; far pairs contribute exactly 0 via max.
            float s1 = 0.0f, s2 = 0.0f;
            {
                const float r = __builtin_amdgcn_sqrtf(d20);
                const float a = fmaxf(fmaf(-10.0f, r, 1.0f), 0.0f);
                const float b = fmaxf(fmaf(-20.0f, r, 1.0f), 0.0f);
                s1 = fmaf(a * a, a, s1);
                s2 = fmaf(b * b, b, s2);
            }
            {
                const float r = __builtin_amdgcn_sqrtf(d21);
                const float a = fmaxf(fmaf(-10.0f, r, 1.0f), 0.0f);
                const float b = fmaxf(fmaf(-20.0f, r, 1.0f), 0.0f);
                s1 = fmaf(a * a, a, s1);
                s2 = fmaf(b * b, b, s2);
            }
            {
                const float r = __builtin_amdgcn_sqrtf(d22);
                const float a = fmaxf(fmaf(-10.0f, r, 1.0f), 0.0f);
                const float b = fmaxf(fmaf(-20.0f, r, 1.0f), 0.0f);
                s1 = fmaf(a * a, a, s1);
                s2 = fmaf(b * b, b, s2);
            }
            {
                const float r = __builtin_amdgcn_sqrtf(d23);
                const float a = fmaxf(fmaf(-10.0f, r, 1.0f), 0.0f);
                const float b = fmaxf(fmaf(-20.0f, r, 1.0f), 0.0f);
                s1 = fmaf(a * a, a, s1);
                s2 = fmaf(b * b, b, s2);
            }
            float wl = fmaf(2.0f, s1, -s2);     // this lane's 4-pair sum
            // Wave butterfly: every lane ends with the 256-pair total.
            wl += __shfl_xor(wl, 32, 64);
            wl += __shfl_xor(wl, 16, 64);
            wl += __shfl_xor(wl, 8, 64);
            wl += __shfl_xor(wl, 4, 64);
            wl += __shfl_xor(wl, 2, 64);
            wl += __shfl_xor(wl, 1, 64);
            accown += (lane == k) ? wl : 0.0f;  // lane k owns i = ibase + k
        }
    }

    ws[(size_t)bj * NPART + ibase + lane] = accown;
}

// Reduce the NSPLITJ partials per particle (fixed order) and scale.
__global__ __launch_bounds__(256) void sph_reduce(const float* __restrict__ ws,
                                                  float* __restrict__ out) {
    const int i = blockIdx.x * 256 + threadIdx.x;
    float s = 0.0f;
    for (int k = 0; k < NSPLITJ; ++k) s += ws[(size_t)k * NPART + i];
    // MASS * 8 / (PI * H^3), PI exactly as the reference literal
    const float norm = (float)(8.0 / (3.14159265 * 0.1 * 0.1 * 0.1));
    out[i] = s * norm;
}

extern "C" void kernel_launch(void* const* d_in, const int* in_sizes, int n_in,
                              void* d_out, int out_size, void* d_ws, size_t ws_size,
                              hipStream_t stream) {
    const float* pos = (const float*)d_in[0];
    float*       out = (float*)d_out;
    float*       ws  = (float*)d_ws;   // needs 32*8192*4 = 1 MB (R3 proved >= 2 MB)

    dim3 grid(ITILES, NSPLITJ);        // 32 x 32 = 1024 blocks = 4/CU
    sph_pairs<<<grid, 256, 0, stream>>>(pos, ws);
    sph_reduce<<<NPART / 256, 256, 0, stream>>>(ws, out);
}